// Round 15
// baseline (60.479 us; speedup 1.0000x reference)
//
#include <hip/hip_runtime.h>
#include <hip/hip_bf16.h>

#define HH 256
#define WW 256
#define CC 128
#define NN 4
#define NSS 5
#define LN2F 0.6931471805599453f
#define FSCALE 3.79828245f      // sqrt(10*log2(e)); dot scales by 14.4269504089
#define EPSI 1e-6f
#define ROW8 (WW * CC)          // 32768 B per image row in fp8 (256 px * 128 B)
#define SC 80                   // staged cols per row window (c0-8 .. c0+71)
#define SBYTES (SC * 128)       // 10240 B per staged row

typedef __attribute__((ext_vector_type(4))) float f32x4;

__device__ __forceinline__ void gload_lds16(const void* g, void* l) {
    __builtin_amdgcn_global_load_lds(
        (const __attribute__((address_space(1))) unsigned int*)g,
        (__attribute__((address_space(3))) unsigned int*)l, 16, 0, 0);
}

__device__ __forceinline__ float fast_exp2(float x) {
    float r;
    asm("v_exp_f32 %0, %1" : "=v"(r) : "v"(x));
    return r;
}
__device__ __forceinline__ float fast_log2(float x) {
    float r;
    asm("v_log_f32 %0, %1" : "=v"(r) : "v"(x));
    return r;
}

// ---------------- Kernel A: L2-normalize over C (x FSCALE), NCHW(f32) -> NHWC(fp8 e4m3) ----
// Per-pixel layout: 16 units of 8B (8 channels each); unit u stored at slot u^(px&15).
// Also zeroes d_out (block 0), replacing a separate memset dispatch.
__global__ __launch_bounds__(256) void norm_pack(const float* __restrict__ feat,
                                                 unsigned char* __restrict__ out,
                                                 float* __restrict__ lossout) {
    __shared__ float lds[64][CC + 2];
    __shared__ float psum[4][64];
    __shared__ float inv[64];
    int bid = blockIdx.x;            // n*1024 + h*4 + wq
    if (bid == 0 && threadIdx.x == 0) lossout[0] = 0.f;
    int wq = bid & 3;
    int h = (bid >> 2) & 255;
    int n = bid >> 10;
    int tid = threadIdx.x;
    int p = tid & 63;
    int cg = tid >> 6;
    size_t base = ((size_t)(n * CC) * HH + h) * WW + wq * 64 + p;
    float ss = 0.f;
    #pragma unroll
    for (int i = 0; i < 32; ++i) {
        int c = cg * 32 + i;
        float v = feat[base + (size_t)c * (HH * WW)];
        lds[p][c] = v;
        ss += v * v;
    }
    psum[cg][p] = ss;
    __syncthreads();
    if (tid < 64) {
        float s = psum[0][tid] + psum[1][tid] + psum[2][tid] + psum[3][tid];
        inv[tid] = FSCALE / fmaxf(sqrtf(s), 1e-12f);
    }
    __syncthreads();
    unsigned char* dst = out + (((size_t)n * HH + h) * WW + wq * 64) * CC;
    // 512 chunks of 16B (64 px x 8 chunks); 2 per thread
    #pragma unroll
    for (int k = 0; k < 2; ++k) {
        int j = k * 256 + tid;
        int pp = j >> 3;                 // pixel 0..63
        int c = j & 7;                   // logical 16B chunk (channels 16c..16c+15)
        int slot = c ^ ((pp >> 1) & 7);  // (px&15)>>1 == (pp>>1)&7 (wq*64 = 0 mod 16)
        float iv = inv[pp];
        int cb = c * 16;
        int base0 = cb + ((pp & 1) ? 8 : 0);   // channels for bytes 0-7
        int base1 = cb + ((pp & 1) ? 0 : 8);   // channels for bytes 8-15
        int w0 = 0, w1 = 0, w2 = 0, w3 = 0;
        w0 = __builtin_amdgcn_cvt_pk_fp8_f32(lds[pp][base0+0]*iv, lds[pp][base0+1]*iv, w0, false);
        w0 = __builtin_amdgcn_cvt_pk_fp8_f32(lds[pp][base0+2]*iv, lds[pp][base0+3]*iv, w0, true);
        w1 = __builtin_amdgcn_cvt_pk_fp8_f32(lds[pp][base0+4]*iv, lds[pp][base0+5]*iv, w1, false);
        w1 = __builtin_amdgcn_cvt_pk_fp8_f32(lds[pp][base0+6]*iv, lds[pp][base0+7]*iv, w1, true);
        w2 = __builtin_amdgcn_cvt_pk_fp8_f32(lds[pp][base1+0]*iv, lds[pp][base1+1]*iv, w2, false);
        w2 = __builtin_amdgcn_cvt_pk_fp8_f32(lds[pp][base1+2]*iv, lds[pp][base1+3]*iv, w2, true);
        w3 = __builtin_amdgcn_cvt_pk_fp8_f32(lds[pp][base1+4]*iv, lds[pp][base1+5]*iv, w3, false);
        w3 = __builtin_amdgcn_cvt_pk_fp8_f32(lds[pp][base1+6]*iv, lds[pp][base1+7]*iv, w3, true);
        int4 wv = {w0, w1, w2, w3};
        *(int4*)(dst + pp * 128 + slot * 16) = wv;
    }
}

// ---------------- Kernel B: LDS-staged banded-Gram FP8-MFMA loss, 8 rows/wave ----------------
// Block = 4 waves, owns 8 rows x 64 cols; wave = 8 own rows x 16 cols. Two fp8
// B-tiles (-8,+8) per staged row shared by ALL 8 A-row fragments.
// R15: two-stage static software pipeline over t — ISSUE(t+1)'s 8 independent
// MFMAs go to the matrix pipe BEFORE PROC(t)'s exp chain reads c(t), so the
// VALU exp work executes under MFMA latency (separate pipes, m114). No setprio
// (lockstep structure = m190's negative regime). Alternating named reg sets
// (cA/cB) keep all indices compile-time (rule #20).
// 2x10KB double-buffer, counted vmcnt, two barriers/row. 512 blocks.
// ds_read_b64 B-frags, full-unit XOR u^(px&15): conflict-free.
// Select-before-exp (msel); masks/weights deferred; features pre-scaled so
// exp(logit)=2^d. C layout (dtype-indep): col=lane&15, row=(lane>>4)*4+reg.
__global__ __launch_bounds__(256, 2) void loss_mfma(const char* __restrict__ fn,
                                                    float* __restrict__ out) {
    extern __shared__ char smem[];
    __shared__ float wsum[4];
    int bid = blockIdx.x;
    int swz = (bid & 7) * 64 + (bid >> 3);    // 512 blocks, bijective XCD swizzle
    int n  = swz >> 7;
    int rg = (swz >> 2) & 31;
    int q  = swz & 3;
    int row0 = rg * 8;
    int c0 = q * 64;
    int tid = threadIdx.x;
    int wave = tid >> 6, lane = tid & 63;
    int nloc = lane & 15, kq = lane >> 4;
    int wbase = c0 + wave * 16;
    int sc0 = c0 - 8;

    const char* img = fn + (size_t)n * ((size_t)HH * ROW8);

    // A fragments: own rows row0..row0+7 at col wbase+nloc; unit u=kb*4+kq at slot u^(px&15)
    long a[8][4];
    {
        int px = wbase + nloc;
        int xo = px & 15;
        const char* pb = img + (size_t)row0 * ROW8 + px * 128;
        #pragma unroll
        for (int t = 0; t < 8; ++t) {
            #pragma unroll
            for (int kb = 0; kb < 4; ++kb)
                a[t][kb] = *(const long*)(pb + (((kb * 4 + kq) ^ xo) << 3));
            pb += ROW8;
        }
    }

    // B-fragment LDS offsets (tiles at wbase-8, wbase+8), buffer-local, swizzle-matched
    int boff[2][4];
    #pragma unroll
    for (int j = 0; j < 2; ++j) {
        int colr = wbase - 8 + 16 * j + nloc;     // in [c0-8, c0+71]
        int lcol = colr - sc0;                    // 0..79
        int cc = min(max(colr, 0), WW - 1);       // pixel actually stored there
        #pragma unroll
        for (int kb = 0; kb < 4; ++kb)
            boff[j][kb] = lcol * 128 + (((kb * 4 + kq) ^ (cc & 15)) << 3);
    }

    // selection (tile1 valid?) + any-valid bits per rr; dy/row-invariant
    unsigned msel = 0, mb = 0;
    #pragma unroll
    for (int rr = 0; rr < 4; ++rr) {
        int rm = kq * 4 + rr;
        int dx0 = -8 + nloc - rm, dx1 = 8 + nloc - rm;
        int nc0 = wbase - 8 + nloc, nc1 = wbase + 8 + nloc;
        bool v0 = dx0 >= -NSS && dx0 <= NSS && nc0 >= 0 && nc0 < WW;
        bool v1 = dx1 >= -NSS && dx1 <= NSS && nc1 >= 0 && nc1 < WW;
        if (v1) msel |= 1u << rr;
        if (v0 || v1) mb |= 1u << rr;
    }

    // staging: 640 16B chunks per row; threads get chunk tid, tid+256, and (tid<128) tid+512
    int ss0, ss1, ss2;
    {
        int ch, cc_;
        ch = tid;        cc_ = min(max(sc0 + (ch >> 3), 0), WW - 1); ss0 = cc_ * 128 + ((ch & 7) << 4);
        ch = 256 + tid;  cc_ = min(max(sc0 + (ch >> 3), 0), WW - 1); ss1 = cc_ * 128 + ((ch & 7) << 4);
        ch = 512 + tid;  cc_ = min(max(sc0 + (ch >> 3), 0), WW - 1); ss2 = cc_ * 128 + ((ch & 7) << 4);
    }
#define STAGE(rr_, buf_) { \
    const char* srow_ = img + (size_t)(rr_) * ROW8; \
    gload_lds16(srow_ + ss0, (buf_) + (tid << 4)); \
    gload_lds16(srow_ + ss1, (buf_) + ((256 + tid) << 4)); \
    if (tid < 128) gload_lds16(srow_ + ss2, (buf_) + ((512 + tid) << 4)); \
}

    float ea[8][4], dsm[8][4];
    #pragma unroll
    for (int t = 0; t < 8; ++t)
        #pragma unroll
        for (int rr = 0; rr < 4; ++rr) { ea[t][rr] = EPSI; dsm[t][rr] = 0.f; }

    int rs = max(row0 - NSS, 0);
    int re = min(row0 + 7 + NSS, HH - 1);

    STAGE(rs, smem);

// active-row predicate for own row t at staged row r (static T_)
#define ACT(T_) (r >= row0 + (T_) - NSS && r <= row0 + (T_) + NSS)
// issue the 8 independent MFMAs for row T_ into named regs (no result read)
#define ISSUE_T(T_, C0_, C1_) \
    if (ACT(T_)) { \
        C0_ = (f32x4){0.f, 0.f, 0.f, 0.f}; C1_ = (f32x4){0.f, 0.f, 0.f, 0.f}; \
        _Pragma("unroll") for (int kb = 0; kb < 4; ++kb) \
            C0_ = __builtin_amdgcn_mfma_f32_16x16x32_fp8_fp8(a[T_][kb], b0[kb], C0_, 0, 0, 0); \
        _Pragma("unroll") for (int kb = 0; kb < 4; ++kb) \
            C1_ = __builtin_amdgcn_mfma_f32_16x16x32_fp8_fp8(a[T_][kb], b1[kb], C1_, 0, 0, 0); \
    }
// consume row T_'s results: select + exp + accumulate (VALU/TRANS only)
#define PROC_T(T_, C0_, C1_) \
    if (ACT(T_)) { \
        _Pragma("unroll") for (int rr = 0; rr < 4; ++rr) { \
            float d_ = ((msel >> rr) & 1) ? C1_[rr] : C0_[rr]; \
            ea[T_][rr] += fast_exp2(d_); \
            dsm[T_][rr] += d_; \
        } \
    }

    for (int r = rs; r <= re; ++r) {
        char* cbuf = smem + ((r - rs) & 1) * SBYTES;
        if (r < re) {
            char* nbuf = smem + ((((r - rs) & 1) ^ 1) * SBYTES);
            STAGE(r + 1, nbuf);
            // S(r) done; S(r+1) stays in flight (per-thread stage instr: 3 | 2)
            if (tid < 128) asm volatile("s_waitcnt vmcnt(3)" ::: "memory");
            else           asm volatile("s_waitcnt vmcnt(2)" ::: "memory");
        } else {
            asm volatile("s_waitcnt vmcnt(0)" ::: "memory");
        }
        __builtin_amdgcn_s_barrier();
        asm volatile("" ::: "memory");

        long b0[4], b1[4];
        #pragma unroll
        for (int kb = 0; kb < 4; ++kb) b0[kb] = *(const long*)(cbuf + boff[0][kb]);
        #pragma unroll
        for (int kb = 0; kb < 4; ++kb) b1[kb] = *(const long*)(cbuf + boff[1][kb]);

        // two-stage software pipeline: exp(t) overlaps MFMA(t+1)
        f32x4 cA0, cA1, cB0, cB1;
        ISSUE_T(0, cA0, cA1)
        ISSUE_T(1, cB0, cB1)
        PROC_T (0, cA0, cA1)
        ISSUE_T(2, cA0, cA1)
        PROC_T (1, cB0, cB1)
        ISSUE_T(3, cB0, cB1)
        PROC_T (2, cA0, cA1)
        ISSUE_T(4, cA0, cA1)
        PROC_T (3, cB0, cB1)
        ISSUE_T(5, cB0, cB1)
        PROC_T (4, cA0, cA1)
        ISSUE_T(6, cA0, cA1)
        PROC_T (5, cB0, cB1)
        ISSUE_T(7, cB0, cB1)
        PROC_T (6, cA0, cA1)
        PROC_T (7, cB0, cB1)

        __builtin_amdgcn_s_barrier();
    }

    // Epilogue: deferred masks, weights, reduce (log2 form: ln(x)=LN2*log2(x))
    float acc = 0.f;
    #pragma unroll
    for (int t = 0; t < 8; ++t) {
        int row = row0 + t;
        float nvd = (float)(min(NSS, row) + min(NSS, HH - 1 - row) + 1);
        #pragma unroll
        for (int rr = 0; rr < 4; ++rr) {
            int wm = wbase + kq * 4 + rr;
            int nwd = min(NSS, wm) + min(NSS, WW - 1 - wm) + 1;
            float iw = LN2F / (nvd * (float)nwd);
            float m_ = (mb & (1u << rr)) ? 1.0f : 0.0f;
            acc += m_ * iw * (nvd * fast_log2(ea[t][rr]) - dsm[t][rr]);
        }
    }

    float tot = acc * (1.0f / (4.0f * 65536.0f));
    #pragma unroll
    for (int off = 32; off >= 1; off >>= 1)
        tot += __shfl_down(tot, off);
    if (lane == 0) wsum[wave] = tot;
    __syncthreads();
    if (tid == 0) atomicAdd(out, wsum[0] + wsum[1] + wsum[2] + wsum[3]);
}

extern "C" void kernel_launch(void* const* d_in, const int* in_sizes, int n_in,
                              void* d_out, int out_size, void* d_ws, size_t ws_size,
                              hipStream_t stream) {
    const float* feat = (const float*)d_in[0];
    float* out = (float*)d_out;
    unsigned char* fnorm = (unsigned char*)d_ws;  // 32MB fp8

    hipFuncSetAttribute(reinterpret_cast<const void*>(&loss_mfma),
                        hipFuncAttributeMaxDynamicSharedMemorySize, 2 * SBYTES);

    norm_pack<<<NN * HH * (WW / 64), 256, 0, stream>>>(feat, fnorm, out);
    loss_mfma<<<NN * 32 * 4, 256, 2 * SBYTES, stream>>>((const char*)fnorm, out);
}

// Round 16
// 59.232 us; speedup vs baseline: 1.0211x; 1.0211x over previous
//
#include <hip/hip_runtime.h>
#include <hip/hip_bf16.h>

#define HH 256
#define WW 256
#define CC 128
#define NN 4
#define NSS 5
#define LN2F 0.6931471805599453f
#define FSCALE 3.79828245f      // sqrt(10*log2(e)); dot scales by 14.4269504089
#define EPSI 1e-6f
#define ROW8 (WW * CC)          // 32768 B per image row in fp8 (256 px * 128 B)
#define SC 80                   // staged cols per row window (c0-8 .. c0+71)
#define SBYTES (SC * 128)       // 10240 B per staged row

typedef __attribute__((ext_vector_type(4))) float f32x4;

__device__ __forceinline__ void gload_lds16(const void* g, void* l) {
    __builtin_amdgcn_global_load_lds(
        (const __attribute__((address_space(1))) unsigned int*)g,
        (__attribute__((address_space(3))) unsigned int*)l, 16, 0, 0);
}

__device__ __forceinline__ float fast_exp2(float x) {
    float r;
    asm("v_exp_f32 %0, %1" : "=v"(r) : "v"(x));
    return r;
}
__device__ __forceinline__ float fast_log2(float x) {
    float r;
    asm("v_log_f32 %0, %1" : "=v"(r) : "v"(x));
    return r;
}

// ---------------- Kernel A: L2-normalize over C (x FSCALE), NCHW(f32) -> NHWC(fp8 e4m3) ----
// Per-pixel layout: 16 units of 8B (8 channels each); unit u stored at slot u^(px&15).
// Also zeroes d_out (block 0), replacing a separate memset dispatch.
__global__ __launch_bounds__(256) void norm_pack(const float* __restrict__ feat,
                                                 unsigned char* __restrict__ out,
                                                 float* __restrict__ lossout) {
    __shared__ float lds[64][CC + 2];
    __shared__ float psum[4][64];
    __shared__ float inv[64];
    int bid = blockIdx.x;            // n*1024 + h*4 + wq
    if (bid == 0 && threadIdx.x == 0) lossout[0] = 0.f;
    int wq = bid & 3;
    int h = (bid >> 2) & 255;
    int n = bid >> 10;
    int tid = threadIdx.x;
    int p = tid & 63;
    int cg = tid >> 6;
    size_t base = ((size_t)(n * CC) * HH + h) * WW + wq * 64 + p;
    float ss = 0.f;
    #pragma unroll
    for (int i = 0; i < 32; ++i) {
        int c = cg * 32 + i;
        float v = feat[base + (size_t)c * (HH * WW)];
        lds[p][c] = v;
        ss += v * v;
    }
    psum[cg][p] = ss;
    __syncthreads();
    if (tid < 64) {
        float s = psum[0][tid] + psum[1][tid] + psum[2][tid] + psum[3][tid];
        inv[tid] = FSCALE / fmaxf(sqrtf(s), 1e-12f);
    }
    __syncthreads();
    unsigned char* dst = out + (((size_t)n * HH + h) * WW + wq * 64) * CC;
    // 512 chunks of 16B (64 px x 8 chunks); 2 per thread
    #pragma unroll
    for (int k = 0; k < 2; ++k) {
        int j = k * 256 + tid;
        int pp = j >> 3;                 // pixel 0..63
        int c = j & 7;                   // logical 16B chunk (channels 16c..16c+15)
        int slot = c ^ ((pp >> 1) & 7);  // (px&15)>>1 == (pp>>1)&7 (wq*64 = 0 mod 16)
        float iv = inv[pp];
        int cb = c * 16;
        int base0 = cb + ((pp & 1) ? 8 : 0);   // channels for bytes 0-7
        int base1 = cb + ((pp & 1) ? 0 : 8);   // channels for bytes 8-15
        int w0 = 0, w1 = 0, w2 = 0, w3 = 0;
        w0 = __builtin_amdgcn_cvt_pk_fp8_f32(lds[pp][base0+0]*iv, lds[pp][base0+1]*iv, w0, false);
        w0 = __builtin_amdgcn_cvt_pk_fp8_f32(lds[pp][base0+2]*iv, lds[pp][base0+3]*iv, w0, true);
        w1 = __builtin_amdgcn_cvt_pk_fp8_f32(lds[pp][base0+4]*iv, lds[pp][base0+5]*iv, w1, false);
        w1 = __builtin_amdgcn_cvt_pk_fp8_f32(lds[pp][base0+6]*iv, lds[pp][base0+7]*iv, w1, true);
        w2 = __builtin_amdgcn_cvt_pk_fp8_f32(lds[pp][base1+0]*iv, lds[pp][base1+1]*iv, w2, false);
        w2 = __builtin_amdgcn_cvt_pk_fp8_f32(lds[pp][base1+2]*iv, lds[pp][base1+3]*iv, w2, true);
        w3 = __builtin_amdgcn_cvt_pk_fp8_f32(lds[pp][base1+4]*iv, lds[pp][base1+5]*iv, w3, false);
        w3 = __builtin_amdgcn_cvt_pk_fp8_f32(lds[pp][base1+6]*iv, lds[pp][base1+7]*iv, w3, true);
        int4 wv = {w0, w1, w2, w3};
        *(int4*)(dst + pp * 128 + slot * 16) = wv;
    }
}

// ---------------- Kernel B: LDS-staged banded-Gram FP8-MFMA loss, 8 rows/wave, ROW PAIRS ----
// Block = 4 waves, owns 8 rows x 64 cols; wave = 8 own rows x 16 cols. Two fp8
// B-tiles (-8,+8) per staged row shared by ALL 8 A-row fragments.
// R16: each barrier phase stages AND computes a PAIR of rows (2x10KB pair
// regions, 40KB total): iterations 18 -> 9, barrier/vmcnt events halved, and
// 16 ds_reads + ~10 MFMA clusters + ~40 exps per phase give 2x the ILP pool
// per latency wait. Odd windows clamp the trailing stage row (always issue the
// same load count so per-wave vmcnt arithmetic stays exact: 6|4 per pair).
// ds_read_b64 B-frags, full-unit XOR u^(px&15): conflict-free.
// Select-before-exp (msel); masks/weights deferred; features pre-scaled so
// exp(logit)=2^d. C layout (dtype-indep): col=lane&15, row=(lane>>4)*4+reg.
__global__ __launch_bounds__(256, 2) void loss_mfma(const char* __restrict__ fn,
                                                    float* __restrict__ out) {
    extern __shared__ char smem[];
    __shared__ float wsum[4];
    int bid = blockIdx.x;
    int swz = (bid & 7) * 64 + (bid >> 3);    // 512 blocks, bijective XCD swizzle
    int n  = swz >> 7;
    int rg = (swz >> 2) & 31;
    int q  = swz & 3;
    int row0 = rg * 8;
    int c0 = q * 64;
    int tid = threadIdx.x;
    int wave = tid >> 6, lane = tid & 63;
    int nloc = lane & 15, kq = lane >> 4;
    int wbase = c0 + wave * 16;
    int sc0 = c0 - 8;

    const char* img = fn + (size_t)n * ((size_t)HH * ROW8);

    // A fragments: own rows row0..row0+7 at col wbase+nloc; unit u=kb*4+kq at slot u^(px&15)
    long a[8][4];
    {
        int px = wbase + nloc;
        int xo = px & 15;
        const char* pb = img + (size_t)row0 * ROW8 + px * 128;
        #pragma unroll
        for (int t = 0; t < 8; ++t) {
            #pragma unroll
            for (int kb = 0; kb < 4; ++kb)
                a[t][kb] = *(const long*)(pb + (((kb * 4 + kq) ^ xo) << 3));
            pb += ROW8;
        }
    }

    // B-fragment LDS offsets (tiles at wbase-8, wbase+8), buffer-local, swizzle-matched
    int boff[2][4];
    #pragma unroll
    for (int j = 0; j < 2; ++j) {
        int colr = wbase - 8 + 16 * j + nloc;     // in [c0-8, c0+71]
        int lcol = colr - sc0;                    // 0..79
        int cc = min(max(colr, 0), WW - 1);       // pixel actually stored there
        #pragma unroll
        for (int kb = 0; kb < 4; ++kb)
            boff[j][kb] = lcol * 128 + (((kb * 4 + kq) ^ (cc & 15)) << 3);
    }

    // selection (tile1 valid?) + any-valid bits per rr; dy/row-invariant
    unsigned msel = 0, mb = 0;
    #pragma unroll
    for (int rr = 0; rr < 4; ++rr) {
        int rm = kq * 4 + rr;
        int dx0 = -8 + nloc - rm, dx1 = 8 + nloc - rm;
        int nc0 = wbase - 8 + nloc, nc1 = wbase + 8 + nloc;
        bool v0 = dx0 >= -NSS && dx0 <= NSS && nc0 >= 0 && nc0 < WW;
        bool v1 = dx1 >= -NSS && dx1 <= NSS && nc1 >= 0 && nc1 < WW;
        if (v1) msel |= 1u << rr;
        if (v0 || v1) mb |= 1u << rr;
    }

    // staging: 640 16B chunks per row; threads get chunk tid, tid+256, and (tid<128) tid+512
    int ss0, ss1, ss2;
    {
        int ch, cc_;
        ch = tid;        cc_ = min(max(sc0 + (ch >> 3), 0), WW - 1); ss0 = cc_ * 128 + ((ch & 7) << 4);
        ch = 256 + tid;  cc_ = min(max(sc0 + (ch >> 3), 0), WW - 1); ss1 = cc_ * 128 + ((ch & 7) << 4);
        ch = 512 + tid;  cc_ = min(max(sc0 + (ch >> 3), 0), WW - 1); ss2 = cc_ * 128 + ((ch & 7) << 4);
    }
#define STAGE(rr_, buf_) { \
    const char* srow_ = img + (size_t)(rr_) * ROW8; \
    gload_lds16(srow_ + ss0, (buf_) + (tid << 4)); \
    gload_lds16(srow_ + ss1, (buf_) + ((256 + tid) << 4)); \
    if (tid < 128) gload_lds16(srow_ + ss2, (buf_) + ((512 + tid) << 4)); \
}

    float ea[8][4], dsm[8][4];
    #pragma unroll
    for (int t = 0; t < 8; ++t)
        #pragma unroll
        for (int rr = 0; rr < 4; ++rr) { ea[t][rr] = EPSI; dsm[t][rr] = 0.f; }

// compute all active own-rows t against staged row R_ (B-frags B0_,B1_ in regs)
#define COMPROW(R_, B0_, B1_) \
    _Pragma("unroll") \
    for (int t = 0; t < 8; ++t) { \
        if ((R_) >= row0 + t - NSS && (R_) <= row0 + t + NSS) { \
            f32x4 c0 = {0.f, 0.f, 0.f, 0.f}, c1 = {0.f, 0.f, 0.f, 0.f}; \
            __builtin_amdgcn_s_setprio(1); \
            _Pragma("unroll") for (int kb = 0; kb < 4; ++kb) \
                c0 = __builtin_amdgcn_mfma_f32_16x16x32_fp8_fp8(a[t][kb], (B0_)[kb], c0, 0, 0, 0); \
            _Pragma("unroll") for (int kb = 0; kb < 4; ++kb) \
                c1 = __builtin_amdgcn_mfma_f32_16x16x32_fp8_fp8(a[t][kb], (B1_)[kb], c1, 0, 0, 0); \
            __builtin_amdgcn_s_setprio(0); \
            _Pragma("unroll") for (int rr = 0; rr < 4; ++rr) { \
                float d_ = ((msel >> rr) & 1) ? c1[rr] : c0[rr]; \
                ea[t][rr] += fast_exp2(d_); \
                dsm[t][rr] += d_; \
            } \
        } \
    }

    int rs = max(row0 - NSS, 0);
    int re = min(row0 + 7 + NSS, HH - 1);

    char* bufA = smem;                 // pair region A: rows at +0, +SBYTES
    char* bufB = smem + 2 * SBYTES;    // pair region B

    STAGE(rs, bufA);
    STAGE(min(rs + 1, re), bufA + SBYTES);

    int pi = 0;
    for (int r = rs; r <= re; r += 2, ++pi) {
        char* cb = (pi & 1) ? bufB : bufA;
        if (r + 2 <= re) {
            char* nb = (pi & 1) ? bufA : bufB;
            STAGE(r + 2, nb);
            STAGE(min(r + 3, re), nb + SBYTES);
            // pair S(r,r+1) done; pair S(r+2,r+3) stays in flight (6|4 per pair)
            if (tid < 128) asm volatile("s_waitcnt vmcnt(6)" ::: "memory");
            else           asm volatile("s_waitcnt vmcnt(4)" ::: "memory");
        } else {
            asm volatile("s_waitcnt vmcnt(0)" ::: "memory");
        }
        __builtin_amdgcn_s_barrier();
        asm volatile("" ::: "memory");

        bool do2 = (r + 1 <= re);      // block-uniform

        long b0[4], b1[4], b2[4], b3[4];
        #pragma unroll
        for (int kb = 0; kb < 4; ++kb) b0[kb] = *(const long*)(cb + boff[0][kb]);
        #pragma unroll
        for (int kb = 0; kb < 4; ++kb) b1[kb] = *(const long*)(cb + boff[1][kb]);
        if (do2) {
            const char* cb2 = cb + SBYTES;
            #pragma unroll
            for (int kb = 0; kb < 4; ++kb) b2[kb] = *(const long*)(cb2 + boff[0][kb]);
            #pragma unroll
            for (int kb = 0; kb < 4; ++kb) b3[kb] = *(const long*)(cb2 + boff[1][kb]);
        }

        COMPROW(r, b0, b1)
        if (do2) {
            COMPROW(r + 1, b2, b3)
        }

        __builtin_amdgcn_s_barrier();
    }

    // Epilogue: deferred masks, weights, reduce (log2 form: ln(x)=LN2*log2(x))
    float acc = 0.f;
    #pragma unroll
    for (int t = 0; t < 8; ++t) {
        int row = row0 + t;
        float nvd = (float)(min(NSS, row) + min(NSS, HH - 1 - row) + 1);
        #pragma unroll
        for (int rr = 0; rr < 4; ++rr) {
            int wm = wbase + kq * 4 + rr;
            int nwd = min(NSS, wm) + min(NSS, WW - 1 - wm) + 1;
            float iw = LN2F / (nvd * (float)nwd);
            float m_ = (mb & (1u << rr)) ? 1.0f : 0.0f;
            acc += m_ * iw * (nvd * fast_log2(ea[t][rr]) - dsm[t][rr]);
        }
    }

    float tot = acc * (1.0f / (4.0f * 65536.0f));
    #pragma unroll
    for (int off = 32; off >= 1; off >>= 1)
        tot += __shfl_down(tot, off);
    if (lane == 0) wsum[wave] = tot;
    __syncthreads();
    if (tid == 0) atomicAdd(out, wsum[0] + wsum[1] + wsum[2] + wsum[3]);
}

extern "C" void kernel_launch(void* const* d_in, const int* in_sizes, int n_in,
                              void* d_out, int out_size, void* d_ws, size_t ws_size,
                              hipStream_t stream) {
    const float* feat = (const float*)d_in[0];
    float* out = (float*)d_out;
    unsigned char* fnorm = (unsigned char*)d_ws;  // 32MB fp8

    hipFuncSetAttribute(reinterpret_cast<const void*>(&loss_mfma),
                        hipFuncAttributeMaxDynamicSharedMemorySize, 4 * SBYTES);

    norm_pack<<<NN * HH * (WW / 64), 256, 0, stream>>>(feat, fnorm, out);
    loss_mfma<<<NN * 32 * 4, 256, 4 * SBYTES, stream>>>((const char*)fnorm, out);
}